// Round 11
// baseline (1895.683 us; speedup 1.0000x reference)
//
#include <hip/hip_runtime.h>
#include <math.h>

#define Bsz 256
#define Tsz 192
#define Fc 8
#define E0c 32
#define E1c 16
#define Hc 512
#define G4 2048
#define DINP 64
#define K1t 576    // 64 + 512
#define K2t 1024   // 512 + 512
#define NBLK 256
#define KPAD1 584  // 576+8 ushorts (16B-aligned rows)
#define KPAD2 1032 // 1024+8 ushorts
#define LDSB_BYTES (64 * KPAD2 * 2)   // 132096
#define WD_WAIT (1 << 17)             // watchdog: fail-visible (NaN), never hang

typedef __attribute__((ext_vector_type(8))) short short8;
typedef __attribute__((ext_vector_type(4))) float f32x4;
typedef __attribute__((ext_vector_type(4))) uint u32x4;

template<int N> struct IC { static constexpr int v = N; };
template<int C, int CMAX, typename F>
__device__ __forceinline__ void static_for(F&& f) {
    if constexpr (C < CMAX) {
        f(IC<C>{});
        static_for<C + 1, CMAX>(f);
    }
}

static __device__ __forceinline__ float bf2f(ushort u) {
    return __uint_as_float(((uint)u) << 16);
}
static __device__ __forceinline__ ushort f2bf(float f) {
    uint u = __float_as_uint(f);
    u = (u + 0x7fffu + ((u >> 16) & 1u)) >> 16;
    return (ushort)u;
}

// ---------- flagless sentinel protocol (R10 counters motivated) ----------
// R10 evidence: FETCH_SIZE scales with flag-fabric size; sc1 stores are
// write-through/no-allocate, so each publish->observe hop (flag AND data
// first touch) pays an HBM fetch (~900cyc loaded). Two serial HBM RTTs per
// step = the ~6us period. Fix: the data IS the flag. h = og*tanh(c) in
// (-1,1) => bf16 0xFFFF (-NaN) is unreachable from f2bf. h buffers are
// 0xFF-prefilled; each address written exactly once (sentinel -> value,
// 2B-aligned stores are per-ushort atomic). Consumers retry sc1 data loads
// until no lane sees 0xFFFF: ONE HBM RTT per step, zero flags, zero
// barriers, zero drains (next poll's vmcnt(0) drains own stores).
// R9 lesson (container-kill): EVERY retry loop backs off with s_sleep.
static __device__ __forceinline__ u32x4 ld128_sc1(const void* p) {
    u32x4 r;
    asm volatile("global_load_dwordx4 %0, %1, off sc1"
                 : "=v"(r) : "v"((unsigned long long)p));
    return r;
}
static __device__ __forceinline__ uint sent2(uint u) {
    return (uint)(((u & 0xFFFFu) == 0xFFFFu) | ((u >> 16) == 0xFFFFu));
}

// sentinel-gated batch load: KS uint4 chunks at stride 32 ushorts.
// Rule-18 fence (sched_barrier after waitcnt) so the check can't hoist.
template<int KS>
static __device__ __forceinline__ void load_gated(const ushort* p, u32x4* buf) {
    int it = 0;
    while (true) {
        static_for<0, KS>([&](auto Kc) {
            constexpr int ks = decltype(Kc)::v;
            buf[ks] = ld128_sc1(p + ks * 32);
        });
        asm volatile("s_waitcnt vmcnt(0)" ::: "memory");
        __builtin_amdgcn_sched_barrier(0);
        uint bad = 0;
        static_for<0, KS>([&](auto Kc) {
            constexpr int ks = decltype(Kc)::v;
            u32x4 b = buf[ks];
            #pragma unroll
            for (int d = 0; d < 4; ++d) bad |= sent2(b[d]);
        });
        if (!__any((int)bad)) break;
        if (++it >= WD_WAIT) break;     // fail-visible (NaN output), never hang
        __builtin_amdgcn_s_sleep(1);    // ALWAYS back off (R9 lesson)
    }
}

// ---------- build padded bf16 x, time-major [T][B][64] ----------
__global__ __launch_bounds__(256) void build_x_kernel(
    const float* __restrict__ x_cont, const int* __restrict__ cat0,
    const int* __restrict__ cat1, const float* __restrict__ emb0,
    const float* __restrict__ emb1, ushort* __restrict__ x_bf)
{
    int idx = blockIdx.x * 256 + threadIdx.x;
    if (idx >= Tsz * Bsz * DINP) return;
    int d = idx & 63;
    int row = idx >> 6;          // t*B + b
    int t = row >> 8;
    int b = row & 255;
    float v = 0.f;
    if (d < Fc)                  v = x_cont[(b * Tsz + t) * Fc + d];
    else if (d < Fc + E0c)       v = emb0[cat0[b * Tsz + t] * E0c + (d - Fc)];
    else if (d < Fc + E0c + E1c) v = emb1[cat1[b * Tsz + t] * E1c + (d - Fc - E0c)];
    x_bf[idx] = f2bf(v);
}

// ---------- transpose fp32 [K][2048] -> bf16 out[n][coff + k], row stride ldout ----------
__global__ __launch_bounds__(256) void transpose_w_kernel(
    const float* __restrict__ in, ushort* __restrict__ out, int K, int ldout, int coff)
{
    __shared__ float tile[32][33];
    int k0 = blockIdx.x * 32;
    int n0 = blockIdx.y * 32;
    int tx = threadIdx.x & 31, ty = threadIdx.x >> 5;
    #pragma unroll
    for (int p = 0; p < 4; ++p) {
        int k = k0 + ty + p * 8;
        tile[ty + p * 8][tx] = (k < K) ? in[k * G4 + n0 + tx] : 0.f;
    }
    __syncthreads();
    #pragma unroll
    for (int p = 0; p < 4; ++p) {
        int nl = ty + p * 8;
        out[(size_t)(n0 + nl) * ldout + coff + k0 + tx] = f2bf(tile[tx][nl]);
    }
}

// ---------- one layer's persistent loop (per-wave rings + sentinel) ----------
// Group: 64 batch rows, 32 blocks per layer. Block: 64 rows x 64 z-cols
// (4 gates x 16 h-cols). Wave wv owns rows m0+wv*16..+15 end-to-end (R10's
// verified ring structure): phase A/B reads, epilogue rows and h stores all
// stay within ring wv -> NO per-step __syncthreads. Weights in LDS
// (read-only after the single init barrier). h stores sc1, NO drain:
// publication is the value itself (sentinel protocol).
template<int KS_IN, int KS_TOT, int LDA_IN, int KPADv, bool A_GATED>
static __device__ __forceinline__ void run_layer(
    const ushort* __restrict__ Ain,    // [T][B][LDA_IN]
    ushort* __restrict__ hbuf,         // [T][B][512] own h (0xFF-prefilled)
    const ushort* __restrict__ hz,     // [B][512] zeros
    const ushort* __restrict__ Wt,     // [2048][KS_TOT*32] bf16
    const float* __restrict__ bias,
    ushort* B_lds,
    int m0, int j0)
{
    constexpr int KS_R = KS_TOT - KS_IN;
    constexpr int KL = KS_TOT * 32;
    constexpr int SEGS = KL / 8;
    int tid = threadIdx.x;
    int lane = tid & 63, wv = tid >> 6;
    int lane15 = lane & 15, quad = lane >> 4;

    // ---- weights -> LDS once: LDS row = gate*16 + hcol ----
    for (int i = tid; i < 64 * SEGS; i += 256) {
        int row = i / SEGS, seg = i - row * SEGS;
        int gz = (row >> 4) * Hc + j0 + (row & 15);
        *(uint4*)&B_lds[row * KPADv + seg * 8] =
            *(const uint4*)(Wt + (size_t)gz * KL + seg * 8);
    }
    __syncthreads();   // the ONLY block-wide barrier (LDS init)

    float bgate[4];
    #pragma unroll
    for (int gt = 0; gt < 4; ++gt) bgate[gt] = bias[gt * Hc + j0 + lane15];
    float cst[4] = {0.f, 0.f, 0.f, 0.f};

    int arow = m0 + wv * 16 + lane15;    // A-fragment row for this lane
    int crow0 = m0 + wv * 16 + quad * 4; // epilogue batch-row base

    for (int t = 0; t < Tsz; ++t) {
        f32x4 acc[4];
        #pragma unroll
        for (int gt = 0; gt < 4; ++gt) acc[gt] = (f32x4){0.f, 0.f, 0.f, 0.f};

        // ======== phase A: input half ========
        {
            const ushort* p0 = Ain + ((size_t)t * Bsz + arow) * LDA_IN + quad * 8;
            u32x4 bufA[KS_IN];
            if constexpr (A_GATED) {
                load_gated<KS_IN>(p0, bufA);          // h1(t): sentinel-gated
            } else {
                static_for<0, KS_IN>([&](auto Kc) {   // x: plain, dep-free
                    constexpr int ks = decltype(Kc)::v;
                    bufA[ks] = __builtin_bit_cast(u32x4, *(const uint4*)(p0 + ks * 32));
                });
                asm volatile("" ::: "memory");
            }
            static_for<0, KS_IN>([&](auto Kc) {
                constexpr int ks = decltype(Kc)::v;
                short8 av = __builtin_bit_cast(short8, bufA[ks]);
                #pragma unroll
                for (int gt = 0; gt < 4; ++gt) {
                    short8 bfr = *(const short8*)&B_lds[(gt * 16 + lane15) * KPADv + ks * 32 + quad * 8];
                    acc[gt] = __builtin_amdgcn_mfma_f32_16x16x32_bf16(av, bfr, acc[gt], 0, 0, 0);
                }
            });
        }

        // ======== phase B: recurrent half (sentinel-gated on own ring's h) ========
        {
            u32x4 bufB[KS_R];
            if (t == 0) {
                const ushort* p1 = hz + (size_t)arow * Hc + quad * 8;
                static_for<0, KS_R>([&](auto Kc) {
                    constexpr int ks = decltype(Kc)::v;
                    bufB[ks] = __builtin_bit_cast(u32x4, *(const uint4*)(p1 + ks * 32));
                });
                asm volatile("" ::: "memory");
            } else {
                const ushort* p1 = hbuf + ((size_t)(t - 1) * Bsz + arow) * Hc + quad * 8;
                load_gated<KS_R>(p1, bufB);
            }
            static_for<0, KS_R>([&](auto Kc) {
                constexpr int ks = decltype(Kc)::v;
                short8 av = __builtin_bit_cast(short8, bufB[ks]);
                #pragma unroll
                for (int gt = 0; gt < 4; ++gt) {
                    short8 bfr = *(const short8*)&B_lds[(gt * 16 + lane15) * KPADv + (KS_IN + ks) * 32 + quad * 8];
                    acc[gt] = __builtin_amdgcn_mfma_f32_16x16x32_bf16(av, bfr, acc[gt], 0, 0, 0);
                }
            });
        }

        // ======== epilogue: thread owns col j0+lane15, rows crow0..crow0+3 ========
        uint hv[4];
        #pragma unroll
        for (int r = 0; r < 4; ++r) {
            float zi = acc[0][r] + bgate[0];
            float zf = acc[1][r] + bgate[1];
            float zg = acc[2][r] + bgate[2];
            float zo = acc[3][r] + bgate[3];
            float ig = 1.f / (1.f + __expf(-zi));
            float fg = 1.f / (1.f + __expf(-zf));
            float gg = tanhf(zg);
            float og = 1.f / (1.f + __expf(-zo));
            float cn = fg * cst[r] + ig * gg;
            cst[r] = cn;
            float hn = og * tanhf(cn);
            hv[r] = (uint)f2bf(hn);
        }
        {
            // sc1 stores, NO drain/barrier/flag: the values ARE the
            // publication. Next step's poll vmcnt(0) drains them implicitly.
            unsigned long long hb = (unsigned long long)
                &hbuf[((size_t)t * Bsz + crow0) * Hc + j0 + lane15];
            asm volatile(
                "global_store_short %0, %1, off sc1\n\t"
                "global_store_short %0, %2, off offset:1024 sc1\n\t"
                "global_store_short %0, %3, off offset:2048 sc1\n\t"
                "global_store_short %0, %4, off offset:3072 sc1"
                :: "v"(hb), "v"(hv[0]), "v"(hv[1]), "v"(hv[2]), "v"(hv[3])
                : "memory");
        }
    }
}

// ---------- the persistent kernel ----------
// XCD mapping (bid&7) is a LOCALITY HEURISTIC ONLY — correctness relies solely
// on sc1 (L3/HBM) coherence + the sentinel value protocol for cross-block data.
__global__ __launch_bounds__(256, 1) void deepar_persistent(
    const ushort* __restrict__ x_bf,
    const ushort* __restrict__ Wt1, const ushort* __restrict__ Wt2,
    const float* __restrict__ b1, const float* __restrict__ b2,
    ushort* __restrict__ h1, ushort* __restrict__ h2,
    const ushort* __restrict__ hz,
    const float* __restrict__ Wmu, const float* __restrict__ bmu,
    const float* __restrict__ Wsig, const float* __restrict__ bsig,
    float* __restrict__ out)
{
    extern __shared__ ushort B_lds[];

    int bid = blockIdx.x;
    int xcd = bid & 7;
    int g = xcd >> 1;
    int role = xcd & 1;
    int jb = bid >> 3;
    int m0 = g * 64;
    int j0 = jb * 16;

    if (role == 0) {
        run_layer<2, 18, DINP, KPAD1, false>(x_bf, h1, hz, Wt1, b1, B_lds, m0, j0);
        return;
    }
    run_layer<16, 32, Hc, KPAD2, true>(h1, h2, hz, Wt2, b2, B_lds, m0, j0);

    // ---- heads: sentinel-gated reads of h2 (no flags anywhere) ----
    int lane = threadIdx.x & 63, wv = threadIdx.x >> 6;
    float wm[8], wsg[8];
    #pragma unroll
    for (int i = 0; i < 8; ++i) {
        wm[i] = Wmu[lane * 8 + i];
        wsg[i] = Wsig[lane * 8 + i];
    }
    float bmu0 = bmu[0], bsg0 = bsig[0];
    for (int i = jb * 4 + wv; i < 64 * Tsz; i += 128) {
        int b = m0 + (i & 63);
        int t = i >> 6;
        const ushort* hp = h2 + ((size_t)t * Bsz + b) * Hc + lane * 8;
        u32x4 rv;
        {
            int it = 0;
            while (true) {
                rv = ld128_sc1(hp);
                asm volatile("s_waitcnt vmcnt(0)" ::: "memory");
                __builtin_amdgcn_sched_barrier(0);
                uint bad = 0;
                #pragma unroll
                for (int d = 0; d < 4; ++d) bad |= sent2(rv[d]);
                if (!__any((int)bad)) break;
                if (++it >= WD_WAIT) break;   // fail-visible
                __builtin_amdgcn_s_sleep(1);  // always back off
            }
        }
        short8 hvv = __builtin_bit_cast(short8, rv);
        float smu = 0.f, ssg = 0.f;
        #pragma unroll
        for (int e = 0; e < 8; ++e) {
            float f = bf2f((ushort)hvv[e]);
            smu += f * wm[e];
            ssg += f * wsg[e];
        }
        #pragma unroll
        for (int off = 32; off > 0; off >>= 1) {
            smu += __shfl_down(smu, off, 64);
            ssg += __shfl_down(ssg, off, 64);
        }
        if (lane == 0) {
            int oi = b * Tsz + t;
            float sg = ssg + bsg0;
            float sp = sg > 0.f ? sg + log1pf(__expf(-sg)) : log1pf(__expf(sg));
            out[oi] = smu + bmu0;
            out[Bsz * Tsz + oi] = sp;
        }
    }
}

extern "C" void kernel_launch(void* const* d_in, const int* in_sizes, int n_in,
                              void* d_out, int out_size, void* d_ws, size_t ws_size,
                              hipStream_t stream) {
    const float* x_cont = (const float*)d_in[0];
    const int*   cat0   = (const int*)d_in[1];
    const int*   cat1   = (const int*)d_in[2];
    const float* emb0   = (const float*)d_in[3];
    const float* emb1   = (const float*)d_in[4];
    const float* Wk1    = (const float*)d_in[5];
    const float* Wr1    = (const float*)d_in[6];
    const float* b1     = (const float*)d_in[7];
    const float* Wk2    = (const float*)d_in[8];
    const float* Wr2    = (const float*)d_in[9];
    const float* b2     = (const float*)d_in[10];
    const float* Wmu    = (const float*)d_in[11];
    const float* bmu    = (const float*)d_in[12];
    const float* Wsig   = (const float*)d_in[13];
    const float* bsig   = (const float*)d_in[14];
    float* out = (float*)d_out;

    const size_t h_bytes = (size_t)Tsz * Bsz * Hc * 2;   // 50.3 MB each

    char* ws = (char*)d_ws;
    ushort* x_bf  = (ushort*)ws;                               ws += (size_t)Tsz * Bsz * DINP * 2;
    ushort* Wt1   = (ushort*)ws;                               ws += (size_t)G4 * K1t * 2;
    ushort* Wt2   = (ushort*)ws;                               ws += (size_t)G4 * K2t * 2;
    ushort* h1    = (ushort*)ws;                               ws += h_bytes;
    ushort* h2    = (ushort*)ws;                               ws += h_bytes;
    ushort* hz    = (ushort*)ws;                               ws += (size_t)Bsz * Hc * 2;

    // sentinel prefill: 0xFFFF bf16 (-NaN) unreachable from f2bf(h), h in (-1,1)
    hipMemsetAsync(h1, 0xFF, h_bytes, stream);
    hipMemsetAsync(h2, 0xFF, h_bytes, stream);
    hipMemsetAsync(hz, 0, (size_t)Bsz * Hc * 2, stream);

    build_x_kernel<<<(Tsz * Bsz * DINP + 255) / 256, 256, 0, stream>>>(
        x_cont, cat0, cat1, emb0, emb1, x_bf);
    transpose_w_kernel<<<dim3(2, 64), 256, 0, stream>>>(Wk1, Wt1, 56, K1t, 0);
    transpose_w_kernel<<<dim3(16, 64), 256, 0, stream>>>(Wr1, Wt1, Hc, K1t, DINP);
    transpose_w_kernel<<<dim3(16, 64), 256, 0, stream>>>(Wk2, Wt2, Hc, K2t, 0);
    transpose_w_kernel<<<dim3(16, 64), 256, 0, stream>>>(Wr2, Wt2, Hc, K2t, Hc);

    hipFuncSetAttribute((const void*)deepar_persistent,
                        hipFuncAttributeMaxDynamicSharedMemorySize, LDSB_BYTES);
    deepar_persistent<<<dim3(NBLK), dim3(256), LDSB_BYTES, stream>>>(
        x_bf, Wt1, Wt2, b1, b2, h1, h2, hz, Wmu, bmu, Wsig, bsig, out);
}

// Round 12
// 1193.025 us; speedup vs baseline: 1.5890x; 1.5890x over previous
//
#include <hip/hip_runtime.h>
#include <math.h>

#define Bsz 256
#define Tsz 192
#define Fc 8
#define E0c 32
#define E1c 16
#define Hc 512
#define G4 2048
#define DINP 64
#define K1t 576    // 64 + 512
#define K2t 1024   // 512 + 512
#define NBLK 256
#define KPAD1 584  // 576+8 ushorts (16B-aligned rows)
#define KPAD2 1032 // 1024+8 ushorts
#define LDSB_BYTES (64 * KPAD2 * 2)   // 132096
#define SLOT_STRIDE 16                // uints; 64 B per slot
#define RING_U (64 * SLOT_STRIDE)     // uints per (block,wave) ring region: own32+dep32
#define WD_WAIT (1 << 17)             // watchdog: fail-visible, never hang

typedef __attribute__((ext_vector_type(8))) short short8;
typedef __attribute__((ext_vector_type(4))) float f32x4;

template<int N> struct IC { static constexpr int v = N; };
template<int C, int CMAX, typename F>
__device__ __forceinline__ void static_for(F&& f) {
    if constexpr (C < CMAX) {
        f(IC<C>{});
        static_for<C + 1, CMAX>(f);
    }
}

static __device__ __forceinline__ float bf2f(ushort u) {
    return __uint_as_float(((uint)u) << 16);
}
static __device__ __forceinline__ ushort f2bf(float f) {
    uint u = __float_as_uint(f);
    u = (u + 0x7fffu + ((u >> 16) & 1u)) >> 16;
    return (ushort)u;
}

// fast activations: v_exp + v_rcp. R1/R2 verified absmax bit-identical
// (0.001953125) vs libm. Epilogue is ON the serial ring chain -> 4x fewer
// instructions than libm tanhf shortens the step period directly.
static __device__ __forceinline__ float sigm_f(float x) {
    return __builtin_amdgcn_rcpf(1.f + __expf(-x));
}
static __device__ __forceinline__ float tanh_f(float x) {
    return 1.f - 2.f * __builtin_amdgcn_rcpf(1.f + __expf(2.f * x));
}

// ---------- device-scope (sc1 = L3 coherence point) primitives ----------
// Protocol ledger: XCD-L2 flag scope (R4) catastrophic; poll volume (R6),
// line contention (R7) neutral; merged waits (R8) regress; sentinel
// data-polls (R11) regress (16-line retry quantum). R10's per-wave rings +
// private 64B slots + flag-then-plain-load is the proven best; this round
// keeps that fabric byte-identical and only shortens the serial chain.
static __device__ __forceinline__ uint poll_sc1(const uint* p) {
    uint v;
    asm volatile("global_load_dword %0, %1, off sc1\n\t"
                 "s_waitcnt vmcnt(0)"
                 : "=v"(v) : "v"((unsigned long long)p) : "memory");
    return v;
}
static __device__ __forceinline__ void store_slot_sc1(uint* p, uint v) {
    asm volatile("global_store_dword %0, %1, off sc1"
                 :: "v"((unsigned long long)p), "v"(v) : "memory");
}

// ---------- build padded bf16 x, time-major [T][B][64] ----------
__global__ __launch_bounds__(256) void build_x_kernel(
    const float* __restrict__ x_cont, const int* __restrict__ cat0,
    const int* __restrict__ cat1, const float* __restrict__ emb0,
    const float* __restrict__ emb1, ushort* __restrict__ x_bf)
{
    int idx = blockIdx.x * 256 + threadIdx.x;
    if (idx >= Tsz * Bsz * DINP) return;
    int d = idx & 63;
    int row = idx >> 6;          // t*B + b
    int t = row >> 8;
    int b = row & 255;
    float v = 0.f;
    if (d < Fc)                  v = x_cont[(b * Tsz + t) * Fc + d];
    else if (d < Fc + E0c)       v = emb0[cat0[b * Tsz + t] * E0c + (d - Fc)];
    else if (d < Fc + E0c + E1c) v = emb1[cat1[b * Tsz + t] * E1c + (d - Fc - E0c)];
    x_bf[idx] = f2bf(v);
}

// ---------- transpose fp32 [K][2048] -> bf16 out[n][coff + k], row stride ldout ----------
__global__ __launch_bounds__(256) void transpose_w_kernel(
    const float* __restrict__ in, ushort* __restrict__ out, int K, int ldout, int coff)
{
    __shared__ float tile[32][33];
    int k0 = blockIdx.x * 32;
    int n0 = blockIdx.y * 32;
    int tx = threadIdx.x & 31, ty = threadIdx.x >> 5;
    #pragma unroll
    for (int p = 0; p < 4; ++p) {
        int k = k0 + ty + p * 8;
        tile[ty + p * 8][tx] = (k < K) ? in[k * G4 + n0 + tx] : 0.f;
    }
    __syncthreads();
    #pragma unroll
    for (int p = 0; p < 4; ++p) {
        int nl = ty + p * 8;
        out[(size_t)(n0 + nl) * ldout + coff + k0 + tx] = f2bf(tile[tx][nl]);
    }
}

// ---------- per-wave ring poll: one coalesced pass, full readiness ballot ----------
// arr = this wave's private ring array (32 slots x 64B, one per producer jb).
// Returns 32-bit mask (bit j: producer j's flag >= tg). Lanes 32-63 mirror.
static __device__ __forceinline__ uint poll_mask(const uint* arr, uint tg) {
    uint v = poll_sc1(arr + (threadIdx.x & 31) * SLOT_STRIDE);
    unsigned long long bal = __ballot((int)(v >= tg));
    return (uint)bal;
}
static __device__ __forceinline__ void wait_mask(const uint* arr, uint tg, uint need) {
    int it = 0;
    while ((poll_mask(arr, tg) & need) != need) {
        if (++it >= WD_WAIT) break;     // fail-visible, never hang
        __builtin_amdgcn_s_sleep(1);    // ALWAYS back off (R9 lesson)
    }
}
static __device__ __forceinline__ void wait_all(const uint* arr, uint tg) {
    wait_mask(arr, tg, 0xFFFFFFFFu);
}

// ---------- load+MFMA a static chunk range [C0,C1), LDS chunk offset KOFF ----------
template<int C0, int C1, int KOFF, int KPADv>
static __device__ __forceinline__ void load_mfma_range(
    const ushort* p, const ushort* B_lds, int lane15, int quad, f32x4* acc)
{
    uint4 buf[C1 - C0];
    static_for<C0, C1>([&](auto Kc) {
        constexpr int ks = decltype(Kc)::v;
        buf[ks - C0] = *(const uint4*)(p + ks * 32);
    });
    asm volatile("" ::: "memory");
    static_for<C0, C1>([&](auto Kc) {
        constexpr int ks = decltype(Kc)::v;
        short8 av = __builtin_bit_cast(short8, buf[ks - C0]);
        #pragma unroll
        for (int gt = 0; gt < 4; ++gt) {
            short8 bfr = *(const short8*)&B_lds[(gt * 16 + lane15) * KPADv
                                               + (KOFF + ks) * 32 + quad * 8];
            acc[gt] = __builtin_amdgcn_mfma_f32_16x16x32_bf16(av, bfr, acc[gt], 0, 0, 0);
        }
    });
}

// ---------- gated 16-chunk phase: opportunistic half-granular consumption ----------
// Chunk ks (input cols 32ks..32ks+32) depends ONLY on producers 2ks,2ks+1
// (slot j = producer jb, owning cols 16j..16j+16). One poll yields the full
// ballot: all-ready -> bulk path (identical cost to R10); upper half lagging
// -> consume chunks 0-7 (producers 0-15) while stragglers finish.
template<int KOFF, int KPADv>
static __device__ __forceinline__ void gated_phase16(
    const ushort* p, const uint* arr, uint tg,
    const ushort* B_lds, int lane15, int quad, f32x4* acc)
{
    uint m = poll_mask(arr, tg);
    if (m == 0xFFFFFFFFu) {
        load_mfma_range<0, 16, KOFF, KPADv>(p, B_lds, lane15, quad, acc);
    } else {
        wait_mask(arr, tg, 0x0000FFFFu);
        load_mfma_range<0, 8, KOFF, KPADv>(p, B_lds, lane15, quad, acc);
        wait_mask(arr, tg, 0xFFFF0000u);
        load_mfma_range<8, 16, KOFF, KPADv>(p, B_lds, lane15, quad, acc);
    }
}

// ---------- one layer's persistent loop (R10 per-wave rings + chain trims) ----------
// Group: 64 batch rows, 32 blocks per layer. Block: 64 rows x 64 z-cols
// (4 gates x 16 h-cols). Wave wv owns rows m0+wv*16..+15 end-to-end: reads,
// epilogue rows and h stores all stay within ring wv -> NO per-step
// __syncthreads. Weights in LDS (read-only after the one init barrier).
// Steady state: each wave gates its ring, computes, drains its OWN 4
// h-stores (vmcnt(0)), and scatters its flags to consumers' private slots.
template<int KS_IN, int KS_TOT, int LDA_IN, int KPADv, bool HAS_DEP, int FANOUT>
static __device__ __forceinline__ void run_layer(
    const ushort* __restrict__ Ain,    // [T][B][LDA_IN]
    ushort* __restrict__ hbuf,         // [T][B][512] own h
    const ushort* __restrict__ hz,     // [B][512] zeros
    const ushort* __restrict__ Wt,     // [2048][KS_TOT*32] bf16
    const float* __restrict__ bias,
    ushort* B_lds,
    uint* pflags,                      // base of per-(block,wave) ring regions
    int g, int jb, int m0, int j0)
{
    constexpr int KS_R = KS_TOT - KS_IN;   // 16 for both layers
    constexpr int KL = KS_TOT * 32;
    constexpr int SEGS = KL / 8;
    int tid = threadIdx.x;
    int lane = tid & 63, wv = tid >> 6;
    int lane15 = lane & 15, quad = lane >> 4;
    int bid = jb * 8 + g * 2 + (HAS_DEP ? 1 : 0);

    uint* ring = pflags + (size_t)(bid * 4 + wv) * RING_U;
    const uint* own_arr = ring;                     // slots 0..31 (own team)
    const uint* dep_arr = ring + 32 * SLOT_STRIDE;  // slots 0..31 (producer team)

    // publish targets (per-thread, ring wv): lane j<32 -> own-team consumer
    // block j's ring-wv own slot jb; lanes 32-63 (L1 only) -> L2 consumer
    // block (j-32)'s ring-wv dep slot jb.
    uint* pub_dst;
    {
        int j = lane & 31;
        int cons_role = HAS_DEP ? 1 : (lane >> 5);
        int cons_bid = j * 8 + g * 2 + cons_role;
        pub_dst = pflags + (size_t)(cons_bid * 4 + wv) * RING_U
                + ((lane >= 32) ? 32 * SLOT_STRIDE : 0) + jb * SLOT_STRIDE;
    }

    // ---- weights -> LDS once: LDS row = gate*16 + hcol ----
    for (int i = tid; i < 64 * SEGS; i += 256) {
        int row = i / SEGS, seg = i - row * SEGS;
        int gz = (row >> 4) * Hc + j0 + (row & 15);
        *(uint4*)&B_lds[row * KPADv + seg * 8] =
            *(const uint4*)(Wt + (size_t)gz * KL + seg * 8);
    }
    __syncthreads();   // the ONLY block-wide barrier (LDS init)

    float bgate[4];
    #pragma unroll
    for (int gt = 0; gt < 4; ++gt) bgate[gt] = bias[gt * Hc + j0 + lane15];
    float cst[4] = {0.f, 0.f, 0.f, 0.f};

    int arow = m0 + wv * 16 + lane15;    // A-fragment row for this lane
    int crow0 = m0 + wv * 16 + quad * 4; // epilogue batch-row base

    for (int t = 0; t < Tsz; ++t) {
        f32x4 acc[4];
        #pragma unroll
        for (int gt = 0; gt < 4; ++gt) acc[gt] = (f32x4){0.f, 0.f, 0.f, 0.f};

        // ======== phase A: input half ========
        {
            const ushort* p0 = Ain + ((size_t)t * Bsz + arow) * LDA_IN + quad * 8;
            if constexpr (HAS_DEP) {
                // L2: h1(t), dep-gated per half (producers = L1 ring-wv)
                gated_phase16<0, KPADv>(p0, dep_arr, (uint)(t + 1),
                                        B_lds, lane15, quad, acc);
            } else {
                // L1: x, dep-free bulk
                load_mfma_range<0, KS_IN, 0, KPADv>(p0, B_lds, lane15, quad, acc);
            }
        }

        // ======== phase B: recurrent half (own-gated per half) ========
        {
            if (t == 0) {
                const ushort* p1 = hz + (size_t)arow * Hc + quad * 8;
                load_mfma_range<0, KS_R, KS_IN, KPADv>(p1, B_lds, lane15, quad, acc);
            } else {
                const ushort* p1 = hbuf + ((size_t)(t - 1) * Bsz + arow) * Hc + quad * 8;
                gated_phase16<KS_IN, KPADv>(p1, own_arr, (uint)t,
                                            B_lds, lane15, quad, acc);
            }
        }

        // ======== epilogue: thread owns col j0+lane15, rows crow0..crow0+3 ========
        uint hv[4];
        #pragma unroll
        for (int r = 0; r < 4; ++r) {
            float zi = acc[0][r] + bgate[0];
            float zf = acc[1][r] + bgate[1];
            float zg = acc[2][r] + bgate[2];
            float zo = acc[3][r] + bgate[3];
            float ig = sigm_f(zi);
            float fg = sigm_f(zf);
            float gg = tanh_f(zg);
            float og = sigm_f(zo);
            float cn = fg * cst[r] + ig * gg;
            cst[r] = cn;
            float hn = og * tanh_f(cn);
            hv[r] = (uint)f2bf(hn);
        }
        {
            unsigned long long hb = (unsigned long long)
                &hbuf[((size_t)t * Bsz + crow0) * Hc + j0 + lane15];
            asm volatile(
                "global_store_short %0, %1, off sc1\n\t"
                "global_store_short %0, %2, off offset:1024 sc1\n\t"
                "global_store_short %0, %3, off offset:2048 sc1\n\t"
                "global_store_short %0, %4, off offset:3072 sc1\n\t"
                "s_waitcnt vmcnt(0)"
                :: "v"(hb), "v"(hv[0]), "v"(hv[1]), "v"(hv[2]), "v"(hv[3])
                : "memory");
        }
        // per-wave scatter publish (no barrier): this wave's rows are fully
        // at the coherence point; ring-wv consumers only need THESE rows.
        if (lane < FANOUT)
            store_slot_sc1(pub_dst, (uint)(t + 1));
    }
}

// ---------- the persistent kernel ----------
// XCD mapping (bid&7) is a LOCALITY HEURISTIC ONLY — correctness relies solely
// on sc1 (L3) coherence for all cross-block data.
__global__ __launch_bounds__(256, 1) void deepar_persistent(
    const ushort* __restrict__ x_bf,
    const ushort* __restrict__ Wt1, const ushort* __restrict__ Wt2,
    const float* __restrict__ b1, const float* __restrict__ b2,
    ushort* __restrict__ h1, ushort* __restrict__ h2,
    const ushort* __restrict__ hz,
    const float* __restrict__ Wmu, const float* __restrict__ bmu,
    const float* __restrict__ Wsig, const float* __restrict__ bsig,
    float* __restrict__ out, uint* __restrict__ pflags)
{
    extern __shared__ ushort B_lds[];

    int bid = blockIdx.x;
    int xcd = bid & 7;
    int g = xcd >> 1;
    int role = xcd & 1;
    int jb = bid >> 3;
    int m0 = g * 64;
    int j0 = jb * 16;

    if (role == 0) {
        // L1: lanes 0-31 feed own team, lanes 32-63 feed L2 dep arrays
        run_layer<2, 18, DINP, KPAD1, false, 64>(x_bf, h1, hz, Wt1, b1, B_lds,
                                                 pflags, g, jb, m0, j0);
        return;
    }
    run_layer<16, 32, Hc, KPAD2, true, 32>(h1, h2, hz, Wt2, b2, B_lds,
                                           pflags, g, jb, m0, j0);

    // ---- heads: each wave confirms its ring at Tsz; barrier covers all rings ----
    {
        int wv = threadIdx.x >> 6;
        const uint* ring = pflags + (size_t)(bid * 4 + wv) * RING_U;
        wait_all(ring, (uint)Tsz);
    }
    __syncthreads();

    int lane = threadIdx.x & 63, wv = threadIdx.x >> 6;
    float wm[8], wsg[8];
    #pragma unroll
    for (int i = 0; i < 8; ++i) {
        wm[i] = Wmu[lane * 8 + i];
        wsg[i] = Wsig[lane * 8 + i];
    }
    float bmu0 = bmu[0], bsg0 = bsig[0];
    for (int i = jb * 4 + wv; i < 64 * Tsz; i += 128) {
        int b = m0 + (i & 63);
        int t = i >> 6;
        const ushort* hp = h2 + ((size_t)t * Bsz + b) * Hc + lane * 8;
        short8 hvv = *(const short8*)hp;
        float smu = 0.f, ssg = 0.f;
        #pragma unroll
        for (int e = 0; e < 8; ++e) {
            float f = bf2f((ushort)hvv[e]);
            smu += f * wm[e];
            ssg += f * wsg[e];
        }
        #pragma unroll
        for (int off = 32; off > 0; off >>= 1) {
            smu += __shfl_down(smu, off, 64);
            ssg += __shfl_down(ssg, off, 64);
        }
        if (lane == 0) {
            int oi = b * Tsz + t;
            float sg = ssg + bsg0;
            float sp = sg > 0.f ? sg + log1pf(__expf(-sg)) : log1pf(__expf(sg));
            out[oi] = smu + bmu0;
            out[Bsz * Tsz + oi] = sp;
        }
    }
}

extern "C" void kernel_launch(void* const* d_in, const int* in_sizes, int n_in,
                              void* d_out, int out_size, void* d_ws, size_t ws_size,
                              hipStream_t stream) {
    const float* x_cont = (const float*)d_in[0];
    const int*   cat0   = (const int*)d_in[1];
    const int*   cat1   = (const int*)d_in[2];
    const float* emb0   = (const float*)d_in[3];
    const float* emb1   = (const float*)d_in[4];
    const float* Wk1    = (const float*)d_in[5];
    const float* Wr1    = (const float*)d_in[6];
    const float* b1     = (const float*)d_in[7];
    const float* Wk2    = (const float*)d_in[8];
    const float* Wr2    = (const float*)d_in[9];
    const float* b2     = (const float*)d_in[10];
    const float* Wmu    = (const float*)d_in[11];
    const float* bmu    = (const float*)d_in[12];
    const float* Wsig   = (const float*)d_in[13];
    const float* bsig   = (const float*)d_in[14];
    float* out = (float*)d_out;

    const size_t pflags_bytes = (size_t)NBLK * 4 * RING_U * 4;   // 4 MB

    char* ws = (char*)d_ws;
    uint*   pflags = (uint*)ws;                                ws += pflags_bytes;
    ushort* x_bf  = (ushort*)ws;                               ws += (size_t)Tsz * Bsz * DINP * 2;
    ushort* Wt1   = (ushort*)ws;                               ws += (size_t)G4 * K1t * 2;
    ushort* Wt2   = (ushort*)ws;                               ws += (size_t)G4 * K2t * 2;
    ushort* h1    = (ushort*)ws;                               ws += (size_t)Tsz * Bsz * Hc * 2;
    ushort* h2    = (ushort*)ws;                               ws += (size_t)Tsz * Bsz * Hc * 2;
    ushort* hz    = (ushort*)ws;                               ws += (size_t)Bsz * Hc * 2;

    hipMemsetAsync(pflags, 0, pflags_bytes, stream);
    hipMemsetAsync(hz, 0, (size_t)Bsz * Hc * 2, stream);

    build_x_kernel<<<(Tsz * Bsz * DINP + 255) / 256, 256, 0, stream>>>(
        x_cont, cat0, cat1, emb0, emb1, x_bf);
    transpose_w_kernel<<<dim3(2, 64), 256, 0, stream>>>(Wk1, Wt1, 56, K1t, 0);
    transpose_w_kernel<<<dim3(16, 64), 256, 0, stream>>>(Wr1, Wt1, Hc, K1t, DINP);
    transpose_w_kernel<<<dim3(16, 64), 256, 0, stream>>>(Wk2, Wt2, Hc, K2t, 0);
    transpose_w_kernel<<<dim3(16, 64), 256, 0, stream>>>(Wr2, Wt2, Hc, K2t, Hc);

    hipFuncSetAttribute((const void*)deepar_persistent,
                        hipFuncAttributeMaxDynamicSharedMemorySize, LDSB_BYTES);
    deepar_persistent<<<dim3(NBLK), dim3(256), LDSB_BYTES, stream>>>(
        x_bf, Wt1, Wt2, b1, b2, h1, h2, hz, Wmu, bmu, Wsig, bsig, out, pflags);
}